// Round 11
// baseline (193.395 us; speedup 1.0000x reference)
//
#include <hip/hip_runtime.h>
#include <hip/hip_bf16.h>

#define N_NODES 20000
#define N_EDGES 320000
#define IN_DIM  1024
#define H_HEADS 8
#define C_CH    64
#define HC      512
#define LEAKY   0.2f
#define LN_EPS  1e-5f

// Extended (transposed) weight: rows 0..511 = W_src cols, 512..519 = att_src fold,
// 520..527 = att_dst fold, 528..639 zero pad (to 5 x 128-col tiles).
// wbT[col][k], bf16.
#define BCOLS 640

typedef short bf16x8 __attribute__((ext_vector_type(8)));
typedef float f32x4  __attribute__((ext_vector_type(4)));

__device__ __forceinline__ unsigned short f2bf(float f) {
    union { float f; unsigned int u; } c; c.f = f;
    unsigned int u = c.u;
    unsigned int r = (u + 0x7fffu + ((u >> 16) & 1u)) >> 16;   // RNE
    return (unsigned short)r;
}
__device__ __forceinline__ float bf2f(unsigned int h) {
    union { unsigned int u; float f; } c; c.u = h << 16; return c.f;
}
__device__ __forceinline__ void gload_lds16(const void* g, void* l) {
    __builtin_amdgcn_global_load_lds(
        (const __attribute__((address_space(1))) unsigned int*)g,
        (__attribute__((address_space(3))) unsigned int*)l, 16, 0, 0);
}

// ---------------------------------------------------------------------------
// Fused: blocks [0,1250) do deg histogram; blocks [1250,3298) convert x->bf16.
#define DEG_BLOCKS 1250
#define CONV_BLOCKS 2048

__global__ __launch_bounds__(256) void fused_pre(
        const float* __restrict__ x, short* __restrict__ xb,
        const int* __restrict__ ei, int* __restrict__ deg) {
    int t = threadIdx.x;
    if (blockIdx.x < DEG_BLOCKS) {
        int e = blockIdx.x * 256 + t;                 // 1250*256 == N_EDGES exactly
        atomicAdd(&deg[ei[N_EDGES + e]], 1);
        return;
    }
    int bid = blockIdx.x - DEG_BLOCKS;
    const int total = N_NODES * IN_DIM / 8;
    int stride = CONV_BLOCKS * 256;
    for (int i = bid * 256 + t; i < total; i += stride) {
        float4 a = ((const float4*)x)[(size_t)i * 2];
        float4 b = ((const float4*)x)[(size_t)i * 2 + 1];
        uint4 r;
        r.x = (unsigned int)f2bf(a.x) | ((unsigned int)f2bf(a.y) << 16);
        r.y = (unsigned int)f2bf(a.z) | ((unsigned int)f2bf(a.w) << 16);
        r.z = (unsigned int)f2bf(b.x) | ((unsigned int)f2bf(b.y) << 16);
        r.w = (unsigned int)f2bf(b.z) | ((unsigned int)f2bf(b.w) << 16);
        *(uint4*)(&xb[(size_t)i * 8]) = r;
    }
}

// ---------------------------------------------------------------------------
// Build wbT (bf16, [BCOLS][IN_DIM]).  grid = 1024 prep blocks + 1 scan tail
// block.  Scan is vectorized: 125 threads x 160 elements (40 x int4).
__global__ void prep_w_scan(const float* __restrict__ Wsrc,
                            const float* __restrict__ Wdst,
                            const float* __restrict__ att_src,
                            const float* __restrict__ att_dst,
                            short* __restrict__ wbT,
                            const int* __restrict__ deg,
                            int* __restrict__ off,
                            int* __restrict__ cursor) {
    int t = threadIdx.x;                  // block = 128 threads

    if (blockIdx.x == IN_DIM) {           // ---- scan tail block
        __shared__ int wtot[2];
        int lane = t & 63, w = t >> 6;
        const int4* deg4 = (const int4*)deg;
        int s = 0;
        if (t < 125) {                    // 125*160 == N_NODES exactly
            #pragma unroll
            for (int j = 0; j < 40; ++j) {
                int4 u = deg4[t * 40 + j];
                s += u.x + u.y + u.z + u.w;
            }
        }
        int v = s;
        #pragma unroll
        for (int o = 1; o < 64; o <<= 1) {
            int u = __shfl_up(v, o);
            if (lane >= o) v += u;
        }
        if (lane == 63) wtot[w] = v;
        __syncthreads();
        int add = (w == 1) ? wtot[0] : 0;
        int run = add + v - s;            // exclusive prefix of this segment
        if (t < 125) {
            int4* off4 = (int4*)off;
            int4* cur4 = (int4*)cursor;
            #pragma unroll
            for (int j = 0; j < 40; ++j) {
                int4 u = deg4[t * 40 + j];
                int4 o_;
                o_.x = run;
                o_.y = o_.x + u.x;
                o_.z = o_.y + u.y;
                o_.w = o_.z + u.z;
                off4[t * 40 + j] = o_;
                cur4[t * 40 + j] = o_;
                run = o_.w + u.w;
            }
            if (t == 124) off[N_NODES] = run;
        }
        return;
    }

    int k = blockIdx.x;
    float4 v = *(const float4*)(Wsrc + (size_t)k * HC + t * 4);
    wbT[(size_t)(t * 4 + 0) * IN_DIM + k] = (short)f2bf(v.x);
    wbT[(size_t)(t * 4 + 1) * IN_DIM + k] = (short)f2bf(v.y);
    wbT[(size_t)(t * 4 + 2) * IN_DIM + k] = (short)f2bf(v.z);
    wbT[(size_t)(t * 4 + 3) * IN_DIM + k] = (short)f2bf(v.w);
    if (t < 16) {
        int h = t & 7;
        const float* W   = (t < 8) ? Wsrc : Wdst;
        const float* att = (t < 8) ? att_src : att_dst;
        float s = 0.f;
        #pragma unroll
        for (int c = 0; c < C_CH; ++c)
            s += W[(size_t)k * HC + h * C_CH + c] * att[h * C_CH + c];
        wbT[(size_t)(512 + t) * IN_DIM + k] = (short)f2bf(s);
    }
    // zero pad cols 528..639
    for (int j = 528 + t; j < BCOLS; j += 128)
        wbT[(size_t)j * IN_DIM + k] = 0;
}

// ---------------------------------------------------------------------------
// MFMA GEMM: counted-vmcnt DOUBLE BUFFER that preserves occupancy.
// BK=32, BN=128 -> A and B are each 512 LDS slots/buffer (8 KB), so the
// whole double buffer is 32 KB (~3 blocks/CU, same as single-buffer) AND
// staging is a uniform 4 loads/thread -> a single compile-time vmcnt(4)
// is correct for every wave.  Per K-step: STAGE(next) -> vmcnt(4) ->
// barrier -> 8 ds_read + 16 MFMA -> barrier.  Loads get a full step of
// latency cover instead of the old issue-then-drain zero cover.
// Coalesced staging + XOR swizzle: slot s = m*4 + kcp holds chunk
// kc = kcp ^ (m&3) of row m (16B chunks) -> 8 lanes read 128B contiguous
// from global; ds_read_b128 spreads 16 lanes 4-way (1.58x, off crit path).
// Blocks [0,NWG): GEMM.  Blocks [NWG,NWG+DEG_BLOCKS): CSR edge scatter.
#define BM 128
#define BN 128
#define BK 32
#define NCOLT (BCOLS / BN)                  // 5
#define NROWT ((N_NODES + BM - 1) / BM)     // 157
#define NWG (NCOLT * NROWT)                 // 785
#define KSTEPS (IN_DIM / BK)                // 32
#define A_SLOTS (BM * BK / 8)               // 512 x 16B = 8 KB
#define B_SLOTS (BN * BK / 8)               // 512 x 16B = 8 KB

__global__ __launch_bounds__(256) void gemm_scatter(
        const short* __restrict__ xb,
        const short* __restrict__ wbT,
        short* __restrict__ xsb,
        float* __restrict__ a_srcv,
        float* __restrict__ a_dstv,
        const int* __restrict__ ei,
        int* __restrict__ cursor,
        int* __restrict__ csr_src) {
    __shared__ short As[2][A_SLOTS * 8];    // 2 x 8 KB
    __shared__ short Bs[2][B_SLOTS * 8];    // 2 x 8 KB   (32 KB total)

    int t = threadIdx.x;

    // ---- scatter blocks: bare CSR scatter, sorted by dst
    if (blockIdx.x >= NWG) {
        int e = (blockIdx.x - NWG) * 256 + t;   // 1250*256 == N_EDGES exactly
        int d = ei[N_EDGES + e];
        int idx = atomicAdd(&cursor[d], 1);
        csr_src[idx] = ei[e];
        return;
    }

    // bijective XCD swizzle (m204): contiguous chunk of wgids per XCD
    int orig = blockIdx.x;
    const int q = NWG >> 3, r = NWG & 7;
    int xcd  = orig & 7;
    int wgid = (xcd < r ? xcd * (q + 1) : r * (q + 1) + (xcd - r) * q) + (orig >> 3);
    int col0 = (wgid % NCOLT) * BN;         // col tiles fastest -> A rows L2-local
    int row0 = (wgid / NCOLT) * BM;

    int lane = t & 63;
    int w    = t >> 6;
    int lr   = lane & 15;
    int lg   = lane >> 4;                   // k-group 0..3
    int wr   = (w >> 1) * 64;               // wave row offset (2x2 waves)
    int wc   = (w & 1) * 64;                // wave col offset
    int kca  = lg ^ (lr & 3);               // swizzled chunk index for frag reads

    // staging source pointers: 2 A slots + 2 B slots per thread (uniform 4).
    // slot s: m(or c) = s>>2, kcp = s&3; source chunk kc = kcp ^ (m&3).
    const short* a_base[2];
    #pragma unroll
    for (int i = 0; i < 2; ++i) {
        int s  = t + 256 * i;               // 0..511
        int m  = s >> 2;
        int kc = (s & 3) ^ (m & 3);
        int gm = row0 + m;
        if (gm >= N_NODES) gm = N_NODES - 1;   // clamp (dead rows, in-bounds)
        a_base[i] = xb + (size_t)gm * IN_DIM + kc * 8;
    }
    const short* b_base[2];
    #pragma unroll
    for (int i = 0; i < 2; ++i) {
        int s  = t + 256 * i;               // 0..511
        int c  = s >> 2;
        int kc = (s & 3) ^ (c & 3);
        b_base[i] = wbT + (size_t)(col0 + c) * IN_DIM + kc * 8;
    }

    f32x4 acc[4][4] = {};

#define STAGE(buf, k0)                                                        \
    do {                                                                      \
        _Pragma("unroll")                                                     \
        for (int i_ = 0; i_ < 2; ++i_)                                        \
            gload_lds16(a_base[i_] + (k0), &As[buf][(t + 256 * i_) * 8]);     \
        _Pragma("unroll")                                                     \
        for (int i_ = 0; i_ < 2; ++i_)                                        \
            gload_lds16(b_base[i_] + (k0), &Bs[buf][(t + 256 * i_) * 8]);     \
    } while (0)

    // prologue: tile 0 in flight
    STAGE(0, 0);

    int cur = 0;
    for (int step = 0; step < KSTEPS; ++step) {
        if (step + 1 < KSTEPS) {
            STAGE(cur ^ 1, (step + 1) * BK);            // issue next (4 loads)
            asm volatile("s_waitcnt vmcnt(4)" ::: "memory");  // cur's 4 done
        } else {
            asm volatile("s_waitcnt vmcnt(0)" ::: "memory");  // peeled drain
        }
        __builtin_amdgcn_s_barrier();

        bf16x8 af[4], bfr[4];
        #pragma unroll
        for (int mi = 0; mi < 4; ++mi)
            af[mi] = *(const bf16x8*)(&As[cur][((wr + mi * 16 + lr) * 4 + kca) * 8]);
        #pragma unroll
        for (int ni = 0; ni < 4; ++ni)
            bfr[ni] = *(const bf16x8*)(&Bs[cur][((wc + ni * 16 + lr) * 4 + kca) * 8]);
        __builtin_amdgcn_s_setprio(1);
        #pragma unroll
        for (int mi = 0; mi < 4; ++mi)
            #pragma unroll
            for (int ni = 0; ni < 4; ++ni)
                acc[mi][ni] = __builtin_amdgcn_mfma_f32_16x16x32_bf16(
                    af[mi], bfr[ni], acc[mi][ni], 0, 0, 0);
        __builtin_amdgcn_s_setprio(0);

        __builtin_amdgcn_s_barrier();       // reads done before next overwrite
        cur ^= 1;
    }
#undef STAGE

    // epilogue: C/D layout col=lane&15, row=(lane>>4)*4+reg
    #pragma unroll
    for (int mi = 0; mi < 4; ++mi) {
        #pragma unroll
        for (int rr = 0; rr < 4; ++rr) {
            int row = row0 + wr + mi * 16 + lg * 4 + rr;
            if (row >= N_NODES) continue;
            #pragma unroll
            for (int ni = 0; ni < 4; ++ni) {
                int col = col0 + wc + ni * 16 + lr;
                float v = acc[mi][ni][rr];
                if (col < 512)      xsb[(size_t)row * HC + col] = (short)f2bf(v);
                else if (col < 520) a_srcv[(size_t)row * 8 + (col - 512)] = v;
                else if (col < 528) a_dstv[(size_t)row * 8 + (col - 520)] = v;
            }
        }
    }
}

// ---------------------------------------------------------------------------
// ONE WAVE per destination node (4 independent waves/block, no barriers).
// Lane owns 8 channels of one head: per edge, one dwordx4 gather per lane,
// one weight compute, 8 FMAs.  LN via 6-step shfl_xor across the wave.
__global__ __launch_bounds__(256) void aggregate_ln(
        const int* __restrict__ off,
        const int* __restrict__ csr_src,
        const float* __restrict__ a_srcv,
        const float* __restrict__ a_dstv,
        const short* __restrict__ xsb,
        const float* __restrict__ bias,
        const float* __restrict__ gamma,
        const float* __restrict__ beta,
        const float* __restrict__ prelu_a,
        float* __restrict__ out) {
    int lane = threadIdx.x & 63;
    int n    = blockIdx.x * 4 + (threadIdx.x >> 6);   // grid 5000 x 4 waves = 20000
    int ch0  = lane * 8;
    int h    = lane >> 3;

    int start = off[n], end = off[n + 1];
    float ad  = a_dstv[(size_t)n * 8 + h];

    float acc[8] = {};
    float wsum = 0.f;

    int i = start;
    for (; i + 1 < end; i += 2) {
        int s0 = __builtin_amdgcn_readfirstlane(csr_src[i]);
        int s1 = __builtin_amdgcn_readfirstlane(csr_src[i + 1]);
        float sc0 = a_srcv[(size_t)s0 * 8 + h] + ad;
        float sc1 = a_srcv[(size_t)s1 * 8 + h] + ad;
        uint4 u0 = *(const uint4*)(xsb + (size_t)s0 * HC + ch0);
        uint4 u1 = *(const uint4*)(xsb + (size_t)s1 * HC + ch0);
        sc0 = (sc0 >= 0.f) ? sc0 : LEAKY * sc0;
        sc1 = (sc1 >= 0.f) ? sc1 : LEAKY * sc1;
        float w0 = __expf(sc0);
        float w1 = __expf(sc1);
        acc[0] = fmaf(w0, bf2f(u0.x & 0xffffu), acc[0]);
        acc[1] = fmaf(w0, bf2f(u0.x >> 16),     acc[1]);
        acc[2] = fmaf(w0, bf2f(u0.y & 0xffffu), acc[2]);
        acc[3] = fmaf(w0, bf2f(u0.y >> 16),     acc[3]);
        acc[4] = fmaf(w0, bf2f(u0.z & 0xffffu), acc[4]);
        acc[5] = fmaf(w0, bf2f(u0.z >> 16),     acc[5]);
        acc[6] = fmaf(w0, bf2f(u0.w & 0xffffu), acc[6]);
        acc[7] = fmaf(w0, bf2f(u0.w >> 16),     acc[7]);
        acc[0] = fmaf(w1, bf2f(u1.x & 0xffffu), acc[0]);
        acc[1] = fmaf(w1, bf2f(u1.x >> 16),     acc[1]);
        acc[2] = fmaf(w1, bf2f(u1.y & 0xffffu), acc[2]);
        acc[3] = fmaf(w1, bf2f(u1.y >> 16),     acc[3]);
        acc[4] = fmaf(w1, bf2f(u1.z & 0xffffu), acc[4]);
        acc[5] = fmaf(w1, bf2f(u1.z >> 16),     acc[5]);
        acc[6] = fmaf(w1, bf2f(u1.w & 0xffffu), acc[6]);
        acc[7] = fmaf(w1, bf2f(u1.w >> 16),     acc[7]);
        wsum += w0 + w1;
    }
    if (i < end) {
        int s0 = __builtin_amdgcn_readfirstlane(csr_src[i]);
        float sc0 = a_srcv[(size_t)s0 * 8 + h] + ad;
        uint4 u0 = *(const uint4*)(xsb + (size_t)s0 * HC + ch0);
        sc0 = (sc0 >= 0.f) ? sc0 : LEAKY * sc0;
        float w0 = __expf(sc0);
        acc[0] = fmaf(w0, bf2f(u0.x & 0xffffu), acc[0]);
        acc[1] = fmaf(w0, bf2f(u0.x >> 16),     acc[1]);
        acc[2] = fmaf(w0, bf2f(u0.y & 0xffffu), acc[2]);
        acc[3] = fmaf(w0, bf2f(u0.y >> 16),     acc[3]);
        acc[4] = fmaf(w0, bf2f(u0.z & 0xffffu), acc[4]);
        acc[5] = fmaf(w0, bf2f(u0.z >> 16),     acc[5]);
        acc[6] = fmaf(w0, bf2f(u0.w & 0xffffu), acc[6]);
        acc[7] = fmaf(w0, bf2f(u0.w >> 16),     acc[7]);
        wsum += w0;
    }

    float inv = 1.f / (wsum + 1e-16f);
    float4 b0 = *(const float4*)(bias + ch0);
    float4 b1 = *(const float4*)(bias + ch0 + 4);
    float v8[8];
    float psum = 0.f, psq = 0.f;
    const float bb[8] = {b0.x, b0.y, b0.z, b0.w, b1.x, b1.y, b1.z, b1.w};
    #pragma unroll
    for (int j = 0; j < 8; ++j) {
        v8[j] = acc[j] * inv + bb[j];
        psum += v8[j];
        psq  += v8[j] * v8[j];
    }
    #pragma unroll
    for (int o = 32; o > 0; o >>= 1) {
        psum += __shfl_xor(psum, o);
        psq  += __shfl_xor(psq, o);
    }
    float mu   = psum * (1.f / (float)HC);
    float var  = psq * (1.f / (float)HC) - mu * mu;
    float rstd = rsqrtf(var + LN_EPS);

    float4 g0 = *(const float4*)(gamma + ch0);
    float4 g1 = *(const float4*)(gamma + ch0 + 4);
    float4 e0 = *(const float4*)(beta + ch0);
    float4 e1 = *(const float4*)(beta + ch0 + 4);
    float4 p0 = *(const float4*)(prelu_a + ch0);
    float4 p1 = *(const float4*)(prelu_a + ch0 + 4);
    const float gg[8] = {g0.x, g0.y, g0.z, g0.w, g1.x, g1.y, g1.z, g1.w};
    const float ee[8] = {e0.x, e0.y, e0.z, e0.w, e1.x, e1.y, e1.z, e1.w};
    const float pp[8] = {p0.x, p0.y, p0.z, p0.w, p1.x, p1.y, p1.z, p1.w};
    float y[8];
    #pragma unroll
    for (int j = 0; j < 8; ++j) {
        float v = (v8[j] - mu) * rstd * gg[j] + ee[j];
        y[j] = (v >= 0.f) ? v : pp[j] * v;
    }
    float4* o4 = (float4*)(out + (size_t)n * HC + ch0);
    o4[0] = make_float4(y[0], y[1], y[2], y[3]);
    o4[1] = make_float4(y[4], y[5], y[6], y[7]);
}

// ---------------------------------------------------------------------------
extern "C" void kernel_launch(void* const* d_in, const int* in_sizes, int n_in,
                              void* d_out, int out_size, void* d_ws, size_t ws_size,
                              hipStream_t stream) {
    const float* x        = (const float*)d_in[0];
    const int*   ei       = (const int*)d_in[2];
    const float* Wsrc     = (const float*)d_in[4];
    const float* Wdst     = (const float*)d_in[5];
    const float* att_src  = (const float*)d_in[6];
    const float* att_dst  = (const float*)d_in[7];
    const float* bias     = (const float*)d_in[8];
    const float* gamma    = (const float*)d_in[9];
    const float* beta     = (const float*)d_in[10];
    const float* prelu_a  = (const float*)d_in[11];
    float* out            = (float*)d_out;

    char*  ws = (char*)d_ws;
    size_t o  = 0;
    auto alloc = [&](size_t bytes) -> void* {
        void* p = ws + o;
        o += (bytes + 255) & ~(size_t)255;
        return p;
    };
    short* wbT     = (short*)alloc(sizeof(short) * BCOLS * IN_DIM);        // 1.31 MB
    short* xsb     = (short*)alloc(sizeof(short) * (size_t)N_NODES * HC);  // 20.5 MB
    float* a_srcv  = (float*)alloc(sizeof(float) * N_NODES * 8);
    float* a_dstv  = (float*)alloc(sizeof(float) * N_NODES * 8);
    int*   deg     = (int*)alloc(sizeof(int) * N_NODES);
    int*   off     = (int*)alloc(sizeof(int) * (N_NODES + 1));
    int*   cursor  = (int*)alloc(sizeof(int) * N_NODES);
    int*   csr_src = (int*)alloc(sizeof(int) * N_EDGES);                   // 1.28 MB

    // xb (bf16 x) lives in d_out: exactly N*1024*2B = N*512*4B; d_out is dead
    // until aggregate_ln fully overwrites it.
    short* xb = (short*)d_out;

    hipMemsetAsync(deg, 0, sizeof(int) * N_NODES, stream);

    fused_pre<<<DEG_BLOCKS + CONV_BLOCKS, 256, 0, stream>>>(x, xb, ei, deg);

    // 1024 prep blocks + 1 scan tail block (scan needs deg from fused_pre)
    prep_w_scan<<<IN_DIM + 1, 128, 0, stream>>>(Wsrc, Wdst, att_src, att_dst,
                                                wbT, deg, off, cursor);

    // GEMM blocks + fused edge_scatter blocks (scatter needs cursor from scan)
    gemm_scatter<<<NWG + DEG_BLOCKS, 256, 0, stream>>>(
        xb, wbT, xsb, a_srcv, a_dstv, ei, cursor, csr_src);

    aggregate_ln<<<N_NODES / 4, 256, 0, stream>>>(
        off, csr_src, a_srcv, a_dstv, xsb, bias, gamma, beta, prelu_a, out);
}

// Round 12
// 154.702 us; speedup vs baseline: 1.2501x; 1.2501x over previous
//
#include <hip/hip_runtime.h>
#include <hip/hip_bf16.h>

#define N_NODES 20000
#define N_EDGES 320000
#define IN_DIM  1024
#define H_HEADS 8
#define C_CH    64
#define HC      512
#define LEAKY   0.2f
#define LN_EPS  1e-5f

// Extended (transposed) weight: rows 0..511 = W_src cols, 512..519 = att_src fold,
// 520..527 = att_dst fold, 528..575 zero pad.  wbT[col][k], bf16.
#define BCOLS 576

typedef short bf16x8 __attribute__((ext_vector_type(8)));
typedef float f32x4  __attribute__((ext_vector_type(4)));

__device__ __forceinline__ unsigned short f2bf(float f) {
    union { float f; unsigned int u; } c; c.f = f;
    unsigned int u = c.u;
    unsigned int r = (u + 0x7fffu + ((u >> 16) & 1u)) >> 16;   // RNE
    return (unsigned short)r;
}
__device__ __forceinline__ float bf2f(unsigned int h) {
    union { unsigned int u; float f; } c; c.u = h << 16; return c.f;
}
__device__ __forceinline__ void gload_lds16(const void* g, void* l) {
    __builtin_amdgcn_global_load_lds(
        (const __attribute__((address_space(1))) unsigned int*)g,
        (__attribute__((address_space(3))) unsigned int*)l, 16, 0, 0);
}

// ---------------------------------------------------------------------------
// Fused: blocks [0,1250) do deg histogram; blocks [1250,3298) convert x->bf16.
#define DEG_BLOCKS 1250
#define CONV_BLOCKS 2048

__global__ __launch_bounds__(256) void fused_pre(
        const float* __restrict__ x, short* __restrict__ xb,
        const int* __restrict__ ei, int* __restrict__ deg) {
    int t = threadIdx.x;
    if (blockIdx.x < DEG_BLOCKS) {
        int e = blockIdx.x * 256 + t;                 // 1250*256 == N_EDGES exactly
        atomicAdd(&deg[ei[N_EDGES + e]], 1);
        return;
    }
    int bid = blockIdx.x - DEG_BLOCKS;
    const int total = N_NODES * IN_DIM / 8;
    int stride = CONV_BLOCKS * 256;
    for (int i = bid * 256 + t; i < total; i += stride) {
        float4 a = ((const float4*)x)[(size_t)i * 2];
        float4 b = ((const float4*)x)[(size_t)i * 2 + 1];
        uint4 r;
        r.x = (unsigned int)f2bf(a.x) | ((unsigned int)f2bf(a.y) << 16);
        r.y = (unsigned int)f2bf(a.z) | ((unsigned int)f2bf(a.w) << 16);
        r.z = (unsigned int)f2bf(b.x) | ((unsigned int)f2bf(b.y) << 16);
        r.w = (unsigned int)f2bf(b.z) | ((unsigned int)f2bf(b.w) << 16);
        *(uint4*)(&xb[(size_t)i * 8]) = r;
    }
}

// ---------------------------------------------------------------------------
// Build wbT (bf16, [BCOLS][IN_DIM]).  grid = 1024 prep blocks + 1 scan tail
// block.  Scan is vectorized: 125 threads x 160 elements (40 x int4).
__global__ void prep_w_scan(const float* __restrict__ Wsrc,
                            const float* __restrict__ Wdst,
                            const float* __restrict__ att_src,
                            const float* __restrict__ att_dst,
                            short* __restrict__ wbT,
                            const int* __restrict__ deg,
                            int* __restrict__ off,
                            int* __restrict__ cursor) {
    int t = threadIdx.x;                  // block = 128 threads

    if (blockIdx.x == IN_DIM) {           // ---- scan tail block
        __shared__ int wtot[2];
        int lane = t & 63, w = t >> 6;
        const int4* deg4 = (const int4*)deg;
        int s = 0;
        if (t < 125) {                    // 125*160 == N_NODES exactly
            #pragma unroll
            for (int j = 0; j < 40; ++j) {
                int4 u = deg4[t * 40 + j];
                s += u.x + u.y + u.z + u.w;
            }
        }
        int v = s;
        #pragma unroll
        for (int o = 1; o < 64; o <<= 1) {
            int u = __shfl_up(v, o);
            if (lane >= o) v += u;
        }
        if (lane == 63) wtot[w] = v;
        __syncthreads();
        int add = (w == 1) ? wtot[0] : 0;
        int run = add + v - s;            // exclusive prefix of this segment
        if (t < 125) {
            int4* off4 = (int4*)off;
            int4* cur4 = (int4*)cursor;
            #pragma unroll
            for (int j = 0; j < 40; ++j) {
                int4 u = deg4[t * 40 + j];
                int4 o_;
                o_.x = run;
                o_.y = o_.x + u.x;
                o_.z = o_.y + u.y;
                o_.w = o_.z + u.z;
                off4[t * 40 + j] = o_;
                cur4[t * 40 + j] = o_;
                run = o_.w + u.w;
            }
            if (t == 124) off[N_NODES] = run;
        }
        return;
    }

    int k = blockIdx.x;
    float4 v = *(const float4*)(Wsrc + (size_t)k * HC + t * 4);
    wbT[(size_t)(t * 4 + 0) * IN_DIM + k] = (short)f2bf(v.x);
    wbT[(size_t)(t * 4 + 1) * IN_DIM + k] = (short)f2bf(v.y);
    wbT[(size_t)(t * 4 + 2) * IN_DIM + k] = (short)f2bf(v.z);
    wbT[(size_t)(t * 4 + 3) * IN_DIM + k] = (short)f2bf(v.w);
    if (t < 16) {
        int h = t & 7;
        const float* W   = (t < 8) ? Wsrc : Wdst;
        const float* att = (t < 8) ? att_src : att_dst;
        float s = 0.f;
        #pragma unroll
        for (int c = 0; c < C_CH; ++c)
            s += W[(size_t)k * HC + h * C_CH + c] * att[h * C_CH + c];
        wbT[(size_t)(512 + t) * IN_DIM + k] = (short)f2bf(s);
    } else if (t < 64) {
        wbT[(size_t)(512 + t) * IN_DIM + k] = 0;   // pad cols 528..575
    }
}

// ---------------------------------------------------------------------------
// MFMA GEMM: SMALL-TILE high-TLP structure + the proven coalesced/swizzled
// layout.  BM=64 x BN=96 x BK=64, 4 waves (2x2, wave tile 32x48), single
// 20 KB LDS buffer -> LDS-cap 8 blocks/CU; grid 1878 GEMM blocks = 7.3/CU
// (vs R10's 3.7) so the 2-barrier lockstep loop is hidden by cross-block
// TLP (m114).  Layout (identical math to R10, 0 bank conflicts measured):
//   LDS slot s = m*8 + kcp holds chunk kc = kcp ^ (m&7) of row m (16B chunks)
//   -> staging: 8 consecutive lanes read 128B contiguous from global;
//   -> fragment ds_read_b128: slot = row*8 + (kc^(lr&7)) -> 2-way = free.
// Blocks [0,NWG): GEMM.  Blocks [NWG,NWG+DEG_BLOCKS): CSR edge scatter.
#define BM 64
#define BN 96
#define BK 64
#define NCOLT (BCOLS / BN)                  // 6
#define NROWT ((N_NODES + BM - 1) / BM)     // 313
#define NWG (NCOLT * NROWT)                 // 1878
#define KSTEPS (IN_DIM / BK)                // 16
#define A_SLOTS (BM * BK / 8)               // 512 x 16B = 8 KB
#define B_SLOTS (BN * BK / 8)               // 768 x 16B = 12 KB

__global__ __launch_bounds__(256) void gemm_scatter(
        const short* __restrict__ xb,
        const short* __restrict__ wbT,
        short* __restrict__ xsb,
        float* __restrict__ a_srcv,
        float* __restrict__ a_dstv,
        const int* __restrict__ ei,
        int* __restrict__ cursor,
        int* __restrict__ csr_src) {
    __shared__ short As[A_SLOTS * 8];       // 8 KB
    __shared__ short Bs[B_SLOTS * 8];       // 12 KB  (20 KB total)

    int t = threadIdx.x;

    // ---- scatter blocks: bare CSR scatter, sorted by dst
    if (blockIdx.x >= NWG) {
        int e = (blockIdx.x - NWG) * 256 + t;   // 1250*256 == N_EDGES exactly
        int d = ei[N_EDGES + e];
        int idx = atomicAdd(&cursor[d], 1);
        csr_src[idx] = ei[e];
        return;
    }

    // bijective XCD swizzle (m204): contiguous chunk of wgids per XCD
    int orig = blockIdx.x;
    const int q = NWG >> 3, r = NWG & 7;
    int xcd  = orig & 7;
    int wgid = (xcd < r ? xcd * (q + 1) : r * (q + 1) + (xcd - r) * q) + (orig >> 3);
    int col0 = (wgid % NCOLT) * BN;         // col tiles fastest -> A rows L2-local
    int row0 = (wgid / NCOLT) * BM;

    int lane = t & 63;
    int w    = t >> 6;
    int lr   = lane & 15;
    int lg   = lane >> 4;                   // k-group 0..3
    int sw   = lr & 7;                      // fragment-read swizzle key
    int wr   = (w >> 1) * 32;               // wave row offset (2x2 waves)
    int wc   = (w & 1) * 48;                // wave col offset

    // staging source pointers: A 2 slots/thread, B 3 slots/thread.
    // slot s: m = s>>3, kcp = s&7; source k-chunk kc = kcp ^ (m&7).
    const short* a_base[2];
    #pragma unroll
    for (int i = 0; i < 2; ++i) {
        int s  = t + 256 * i;               // 0..511
        int m  = s >> 3;
        int kc = (s & 7) ^ (m & 7);
        int gm = row0 + m;
        if (gm >= N_NODES) gm = N_NODES - 1;   // clamp (dead rows, in-bounds)
        a_base[i] = xb + (size_t)gm * IN_DIM + kc * 8;
    }
    const short* b_base[3];
    #pragma unroll
    for (int i = 0; i < 3; ++i) {
        int s  = t + 256 * i;               // 0..767
        int c  = s >> 3;
        int kc = (s & 7) ^ (c & 7);
        b_base[i] = wbT + (size_t)(col0 + c) * IN_DIM + kc * 8;
    }

    f32x4 acc[2][3] = {};

    for (int step = 0; step < KSTEPS; ++step) {
        int k0 = step * BK;
        #pragma unroll
        for (int i = 0; i < 2; ++i)
            gload_lds16(a_base[i] + k0, &As[(t + 256 * i) * 8]);
        #pragma unroll
        for (int i = 0; i < 3; ++i)
            gload_lds16(b_base[i] + k0, &Bs[(t + 256 * i) * 8]);
        asm volatile("s_waitcnt vmcnt(0)" ::: "memory");
        __builtin_amdgcn_s_barrier();

        #pragma unroll
        for (int ks = 0; ks < 2; ++ks) {
            int kc  = ks * 4 + lg;
            int kca = kc ^ sw;              // swizzled chunk index
            bf16x8 af[2], bfr[3];
            #pragma unroll
            for (int mi = 0; mi < 2; ++mi)
                af[mi] = *(const bf16x8*)(&As[((wr + mi * 16 + lr) * 8 + kca) * 8]);
            #pragma unroll
            for (int ni = 0; ni < 3; ++ni)
                bfr[ni] = *(const bf16x8*)(&Bs[((wc + ni * 16 + lr) * 8 + kca) * 8]);
            __builtin_amdgcn_s_setprio(1);
            #pragma unroll
            for (int mi = 0; mi < 2; ++mi)
                #pragma unroll
                for (int ni = 0; ni < 3; ++ni)
                    acc[mi][ni] = __builtin_amdgcn_mfma_f32_16x16x32_bf16(
                        af[mi], bfr[ni], acc[mi][ni], 0, 0, 0);
            __builtin_amdgcn_s_setprio(0);
        }
        __builtin_amdgcn_s_barrier();       // reads done before next overwrite
    }

    // epilogue: C/D layout col=lane&15, row=(lane>>4)*4+reg
    #pragma unroll
    for (int mi = 0; mi < 2; ++mi) {
        #pragma unroll
        for (int rr = 0; rr < 4; ++rr) {
            int row = row0 + wr + mi * 16 + lg * 4 + rr;
            if (row >= N_NODES) continue;
            #pragma unroll
            for (int ni = 0; ni < 3; ++ni) {
                int col = col0 + wc + ni * 16 + lr;
                float v = acc[mi][ni][rr];
                if (col < 512)      xsb[(size_t)row * HC + col] = (short)f2bf(v);
                else if (col < 520) a_srcv[(size_t)row * 8 + (col - 512)] = v;
                else if (col < 528) a_dstv[(size_t)row * 8 + (col - 520)] = v;
            }
        }
    }
}

// ---------------------------------------------------------------------------
// ONE WAVE per destination node (4 independent waves/block, no barriers).
// Lane owns 8 channels of one head: per edge, one dwordx4 gather per lane,
// one weight compute, 8 FMAs.  LN via 6-step shfl_xor across the wave.
__global__ __launch_bounds__(256) void aggregate_ln(
        const int* __restrict__ off,
        const int* __restrict__ csr_src,
        const float* __restrict__ a_srcv,
        const float* __restrict__ a_dstv,
        const short* __restrict__ xsb,
        const float* __restrict__ bias,
        const float* __restrict__ gamma,
        const float* __restrict__ beta,
        const float* __restrict__ prelu_a,
        float* __restrict__ out) {
    int lane = threadIdx.x & 63;
    int n    = blockIdx.x * 4 + (threadIdx.x >> 6);   // grid 5000 x 4 waves = 20000
    int ch0  = lane * 8;
    int h    = lane >> 3;

    int start = off[n], end = off[n + 1];
    float ad  = a_dstv[(size_t)n * 8 + h];

    float acc[8] = {};
    float wsum = 0.f;

    int i = start;
    for (; i + 1 < end; i += 2) {
        int s0 = __builtin_amdgcn_readfirstlane(csr_src[i]);
        int s1 = __builtin_amdgcn_readfirstlane(csr_src[i + 1]);
        float sc0 = a_srcv[(size_t)s0 * 8 + h] + ad;
        float sc1 = a_srcv[(size_t)s1 * 8 + h] + ad;
        uint4 u0 = *(const uint4*)(xsb + (size_t)s0 * HC + ch0);
        uint4 u1 = *(const uint4*)(xsb + (size_t)s1 * HC + ch0);
        sc0 = (sc0 >= 0.f) ? sc0 : LEAKY * sc0;
        sc1 = (sc1 >= 0.f) ? sc1 : LEAKY * sc1;
        float w0 = __expf(sc0);
        float w1 = __expf(sc1);
        acc[0] = fmaf(w0, bf2f(u0.x & 0xffffu), acc[0]);
        acc[1] = fmaf(w0, bf2f(u0.x >> 16),     acc[1]);
        acc[2] = fmaf(w0, bf2f(u0.y & 0xffffu), acc[2]);
        acc[3] = fmaf(w0, bf2f(u0.y >> 16),     acc[3]);
        acc[4] = fmaf(w0, bf2f(u0.z & 0xffffu), acc[4]);
        acc[5] = fmaf(w0, bf2f(u0.z >> 16),     acc[5]);
        acc[6] = fmaf(w0, bf2f(u0.w & 0xffffu), acc[6]);
        acc[7] = fmaf(w0, bf2f(u0.w >> 16),     acc[7]);
        acc[0] = fmaf(w1, bf2f(u1.x & 0xffffu), acc[0]);
        acc[1] = fmaf(w1, bf2f(u1.x >> 16),     acc[1]);
        acc[2] = fmaf(w1, bf2f(u1.y & 0xffffu), acc[2]);
        acc[3] = fmaf(w1, bf2f(u1.y >> 16),     acc[3]);
        acc[4] = fmaf(w1, bf2f(u1.z & 0xffffu), acc[4]);
        acc[5] = fmaf(w1, bf2f(u1.z >> 16),     acc[5]);
        acc[6] = fmaf(w1, bf2f(u1.w & 0xffffu), acc[6]);
        acc[7] = fmaf(w1, bf2f(u1.w >> 16),     acc[7]);
        wsum += w0 + w1;
    }
    if (i < end) {
        int s0 = __builtin_amdgcn_readfirstlane(csr_src[i]);
        float sc0 = a_srcv[(size_t)s0 * 8 + h] + ad;
        uint4 u0 = *(const uint4*)(xsb + (size_t)s0 * HC + ch0);
        sc0 = (sc0 >= 0.f) ? sc0 : LEAKY * sc0;
        float w0 = __expf(sc0);
        acc[0] = fmaf(w0, bf2f(u0.x & 0xffffu), acc[0]);
        acc[1] = fmaf(w0, bf2f(u0.x >> 16),     acc[1]);
        acc[2] = fmaf(w0, bf2f(u0.y & 0xffffu), acc[2]);
        acc[3] = fmaf(w0, bf2f(u0.y >> 16),     acc[3]);
        acc[4] = fmaf(w0, bf2f(u0.z & 0xffffu), acc[4]);
        acc[5] = fmaf(w0, bf2f(u0.z >> 16),     acc[5]);
        acc[6] = fmaf(w0, bf2f(u0.w & 0xffffu), acc[6]);
        acc[7] = fmaf(w0, bf2f(u0.w >> 16),     acc[7]);
        wsum += w0;
    }

    float inv = 1.f / (wsum + 1e-16f);
    float4 b0 = *(const float4*)(bias + ch0);
    float4 b1 = *(const float4*)(bias + ch0 + 4);
    float v8[8];
    float psum = 0.f, psq = 0.f;
    const float bb[8] = {b0.x, b0.y, b0.z, b0.w, b1.x, b1.y, b1.z, b1.w};
    #pragma unroll
    for (int j = 0; j < 8; ++j) {
        v8[j] = acc[j] * inv + bb[j];
        psum += v8[j];
        psq  += v8[j] * v8[j];
    }
    #pragma unroll
    for (int o = 32; o > 0; o >>= 1) {
        psum += __shfl_xor(psum, o);
        psq  += __shfl_xor(psq, o);
    }
    float mu   = psum * (1.f / (float)HC);
    float var  = psq * (1.f / (float)HC) - mu * mu;
    float rstd = rsqrtf(var + LN_EPS);

    float4 g0 = *(const float4*)(gamma + ch0);
    float4 g1 = *(const float4*)(gamma + ch0 + 4);
    float4 e0 = *(const float4*)(beta + ch0);
    float4 e1 = *(const float4*)(beta + ch0 + 4);
    float4 p0 = *(const float4*)(prelu_a + ch0);
    float4 p1 = *(const float4*)(prelu_a + ch0 + 4);
    const float gg[8] = {g0.x, g0.y, g0.z, g0.w, g1.x, g1.y, g1.z, g1.w};
    const float ee[8] = {e0.x, e0.y, e0.z, e0.w, e1.x, e1.y, e1.z, e1.w};
    const float pp[8] = {p0.x, p0.y, p0.z, p0.w, p1.x, p1.y, p1.z, p1.w};
    float y[8];
    #pragma unroll
    for (int j = 0; j < 8; ++j) {
        float v = (v8[j] - mu) * rstd * gg[j] + ee[j];
        y[j] = (v >= 0.f) ? v : pp[j] * v;
    }
    float4* o4 = (float4*)(out + (size_t)n * HC + ch0);
    o4[0] = make_float4(y[0], y[1], y[2], y[3]);
    o4[1] = make_float4(y[4], y[5], y[6], y[7]);
}

// ---------------------------------------------------------------------------
extern "C" void kernel_launch(void* const* d_in, const int* in_sizes, int n_in,
                              void* d_out, int out_size, void* d_ws, size_t ws_size,
                              hipStream_t stream) {
    const float* x        = (const float*)d_in[0];
    const int*   ei       = (const int*)d_in[2];
    const float* Wsrc     = (const float*)d_in[4];
    const float* Wdst     = (const float*)d_in[5];
    const float* att_src  = (const float*)d_in[6];
    const float* att_dst  = (const float*)d_in[7];
    const float* bias     = (const float*)d_in[8];
    const float* gamma    = (const float*)d_in[9];
    const float* beta     = (const float*)d_in[10];
    const float* prelu_a  = (const float*)d_in[11];
    float* out            = (float*)d_out;

    char*  ws = (char*)d_ws;
    size_t o  = 0;
    auto alloc = [&](size_t bytes) -> void* {
        void* p = ws + o;
        o += (bytes + 255) & ~(size_t)255;
        return p;
    };
    short* wbT     = (short*)alloc(sizeof(short) * BCOLS * IN_DIM);        // 1.18 MB
    short* xsb     = (short*)alloc(sizeof(short) * (size_t)N_NODES * HC);  // 20.5 MB
    float* a_srcv  = (float*)alloc(sizeof(float) * N_NODES * 8);
    float* a_dstv  = (float*)alloc(sizeof(float) * N_NODES * 8);
    int*   deg     = (int*)alloc(sizeof(int) * N_NODES);
    int*   off     = (int*)alloc(sizeof(int) * (N_NODES + 1));
    int*   cursor  = (int*)alloc(sizeof(int) * N_NODES);
    int*   csr_src = (int*)alloc(sizeof(int) * N_EDGES);                   // 1.28 MB

    // xb (bf16 x) lives in d_out: exactly N*1024*2B = N*512*4B; d_out is dead
    // until aggregate_ln fully overwrites it.
    short* xb = (short*)d_out;

    hipMemsetAsync(deg, 0, sizeof(int) * N_NODES, stream);

    fused_pre<<<DEG_BLOCKS + CONV_BLOCKS, 256, 0, stream>>>(x, xb, ei, deg);

    // 1024 prep blocks + 1 scan tail block (scan needs deg from fused_pre)
    prep_w_scan<<<IN_DIM + 1, 128, 0, stream>>>(Wsrc, Wdst, att_src, att_dst,
                                                wbT, deg, off, cursor);

    // GEMM blocks + fused edge_scatter blocks (scatter needs cursor from scan)
    gemm_scatter<<<NWG + DEG_BLOCKS, 256, 0, stream>>>(
        xb, wbT, xsb, a_srcv, a_dstv, ei, cursor, csr_src);

    aggregate_ln<<<N_NODES / 4, 256, 0, stream>>>(
        off, csr_src, a_srcv, a_dstv, xsb, bias, gamma, beta, prelu_a, out);
}

// Round 13
// 147.963 us; speedup vs baseline: 1.3070x; 1.0455x over previous
//
#include <hip/hip_runtime.h>
#include <hip/hip_bf16.h>

#define N_NODES 20000
#define N_EDGES 320000
#define IN_DIM  1024
#define H_HEADS 8
#define C_CH    64
#define HC      512
#define LEAKY   0.2f
#define LN_EPS  1e-5f

// Extended (transposed) weight: rows 0..511 = W_src cols, 512..519 = att_src fold,
// 520..527 = att_dst fold, 528..575 zero pad.  wbT[col][k], bf16.
#define BCOLS 576

typedef short bf16x8 __attribute__((ext_vector_type(8)));
typedef float f32x4  __attribute__((ext_vector_type(4)));

__device__ __forceinline__ unsigned short f2bf(float f) {
    union { float f; unsigned int u; } c; c.f = f;
    unsigned int u = c.u;
    unsigned int r = (u + 0x7fffu + ((u >> 16) & 1u)) >> 16;   // RNE
    return (unsigned short)r;
}
__device__ __forceinline__ float bf2f(unsigned int h) {
    union { unsigned int u; float f; } c; c.u = h << 16; return c.f;
}
__device__ __forceinline__ unsigned int bfpack(float lo, float hi) {
    return (unsigned int)f2bf(lo) | ((unsigned int)f2bf(hi) << 16);
}
__device__ __forceinline__ void gload_lds16(const void* g, void* l) {
    __builtin_amdgcn_global_load_lds(
        (const __attribute__((address_space(1))) unsigned int*)g,
        (__attribute__((address_space(3))) unsigned int*)l, 16, 0, 0);
}

// ---------------------------------------------------------------------------
// deg histogram only (the 128 MB x->bf16 conversion pass is GONE — the
// conversion now rides inside the GEMM's A-staging).
#define DEG_BLOCKS 1250

__global__ __launch_bounds__(256) void deg_hist(
        const int* __restrict__ ei, int* __restrict__ deg) {
    int e = blockIdx.x * 256 + threadIdx.x;           // 1250*256 == N_EDGES
    atomicAdd(&deg[ei[N_EDGES + e]], 1);
}

// ---------------------------------------------------------------------------
// Build wbT (bf16, [BCOLS][IN_DIM]).  grid = 1024 prep blocks + 1 scan tail
// block.  Scan is vectorized: 125 threads x 160 elements (40 x int4).
__global__ void prep_w_scan(const float* __restrict__ Wsrc,
                            const float* __restrict__ Wdst,
                            const float* __restrict__ att_src,
                            const float* __restrict__ att_dst,
                            short* __restrict__ wbT,
                            const int* __restrict__ deg,
                            int* __restrict__ off,
                            int* __restrict__ cursor) {
    int t = threadIdx.x;                  // block = 128 threads

    if (blockIdx.x == IN_DIM) {           // ---- scan tail block
        __shared__ int wtot[2];
        int lane = t & 63, w = t >> 6;
        const int4* deg4 = (const int4*)deg;
        int s = 0;
        if (t < 125) {                    // 125*160 == N_NODES exactly
            #pragma unroll
            for (int j = 0; j < 40; ++j) {
                int4 u = deg4[t * 40 + j];
                s += u.x + u.y + u.z + u.w;
            }
        }
        int v = s;
        #pragma unroll
        for (int o = 1; o < 64; o <<= 1) {
            int u = __shfl_up(v, o);
            if (lane >= o) v += u;
        }
        if (lane == 63) wtot[w] = v;
        __syncthreads();
        int add = (w == 1) ? wtot[0] : 0;
        int run = add + v - s;            // exclusive prefix of this segment
        if (t < 125) {
            int4* off4 = (int4*)off;
            int4* cur4 = (int4*)cursor;
            #pragma unroll
            for (int j = 0; j < 40; ++j) {
                int4 u = deg4[t * 40 + j];
                int4 o_;
                o_.x = run;
                o_.y = o_.x + u.x;
                o_.z = o_.y + u.y;
                o_.w = o_.z + u.z;
                off4[t * 40 + j] = o_;
                cur4[t * 40 + j] = o_;
                run = o_.w + u.w;
            }
            if (t == 124) off[N_NODES] = run;
        }
        return;
    }

    int k = blockIdx.x;
    float4 v = *(const float4*)(Wsrc + (size_t)k * HC + t * 4);
    wbT[(size_t)(t * 4 + 0) * IN_DIM + k] = (short)f2bf(v.x);
    wbT[(size_t)(t * 4 + 1) * IN_DIM + k] = (short)f2bf(v.y);
    wbT[(size_t)(t * 4 + 2) * IN_DIM + k] = (short)f2bf(v.z);
    wbT[(size_t)(t * 4 + 3) * IN_DIM + k] = (short)f2bf(v.w);
    if (t < 16) {
        int h = t & 7;
        const float* W   = (t < 8) ? Wsrc : Wdst;
        const float* att = (t < 8) ? att_src : att_dst;
        float s = 0.f;
        #pragma unroll
        for (int c = 0; c < C_CH; ++c)
            s += W[(size_t)k * HC + h * C_CH + c] * att[h * C_CH + c];
        wbT[(size_t)(512 + t) * IN_DIM + k] = (short)f2bf(s);
    } else if (t < 64) {
        wbT[(size_t)(512 + t) * IN_DIM + k] = 0;   // pad cols 528..575
    }
}

// ---------------------------------------------------------------------------
// MFMA GEMM, R12 structure (BM=64 x BN=96 x BK=64, 4 waves 2x2, single 20 KB
// LDS buffer, 1878 blocks = 7.3/CU TLP) with fp32 A read DIRECTLY from x:
// A-staging is reg-staged (2 slots/thread: 2x float4 coalesced load ->
// f2bf pack -> ds_write_b128) producing the IDENTICAL swizzled LDS layout:
//   slot s = m*8 + kcp holds chunk kc = kcp ^ (m&7) of row m (8 bf16 / 32B fp32)
//   -> 8 consecutive lanes cover one 256B row-segment (permuted within) = coalesced;
//   -> fragment ds_read_b128: slot = row*8 + (kc^(lr&7)) -> 2-way = free.
// B stays global_load_lds.  __syncthreads() drains vmcnt+lgkmcnt.
// Blocks [0,NWG): GEMM.  Blocks [NWG,NWG+DEG_BLOCKS): CSR edge scatter.
#define BM 64
#define BN 96
#define BK 64
#define NCOLT (BCOLS / BN)                  // 6
#define NROWT ((N_NODES + BM - 1) / BM)     // 313
#define NWG (NCOLT * NROWT)                 // 1878
#define KSTEPS (IN_DIM / BK)                // 16
#define A_SLOTS (BM * BK / 8)               // 512 x 16B = 8 KB
#define B_SLOTS (BN * BK / 8)               // 768 x 16B = 12 KB

__global__ __launch_bounds__(256) void gemm_scatter(
        const float* __restrict__ x,
        const short* __restrict__ wbT,
        short* __restrict__ xsb,
        float* __restrict__ a_srcv,
        float* __restrict__ a_dstv,
        const int* __restrict__ ei,
        int* __restrict__ cursor,
        int* __restrict__ csr_src) {
    __shared__ short As[A_SLOTS * 8];       // 8 KB
    __shared__ short Bs[B_SLOTS * 8];       // 12 KB  (20 KB total)

    int t = threadIdx.x;

    // ---- scatter blocks: bare CSR scatter, sorted by dst
    if (blockIdx.x >= NWG) {
        int e = (blockIdx.x - NWG) * 256 + t;   // 1250*256 == N_EDGES exactly
        int d = ei[N_EDGES + e];
        int idx = atomicAdd(&cursor[d], 1);
        csr_src[idx] = ei[e];
        return;
    }

    // bijective XCD swizzle (m204): contiguous chunk of wgids per XCD
    int orig = blockIdx.x;
    const int q = NWG >> 3, r = NWG & 7;
    int xcd  = orig & 7;
    int wgid = (xcd < r ? xcd * (q + 1) : r * (q + 1) + (xcd - r) * q) + (orig >> 3);
    int col0 = (wgid % NCOLT) * BN;         // col tiles fastest -> A rows L2-local
    int row0 = (wgid / NCOLT) * BM;

    int lane = t & 63;
    int w    = t >> 6;
    int lr   = lane & 15;
    int lg   = lane >> 4;                   // k-group 0..3
    int sw   = lr & 7;                      // fragment-read swizzle key
    int wr   = (w >> 1) * 32;               // wave row offset (2x2 waves)
    int wc   = (w & 1) * 48;                // wave col offset

    // A staging source (fp32): slot s: m = s>>3, kcp = s&7; chunk kc = kcp^(m&7)
    // covers floats [kc*8, kc*8+8) of row m.
    const float* a_base[2];
    #pragma unroll
    for (int i = 0; i < 2; ++i) {
        int s  = t + 256 * i;               // 0..511
        int m  = s >> 3;
        int kc = (s & 7) ^ (m & 7);
        int gm = row0 + m;
        if (gm >= N_NODES) gm = N_NODES - 1;   // clamp (dead rows, in-bounds)
        a_base[i] = x + (size_t)gm * IN_DIM + kc * 8;
    }
    const short* b_base[3];
    #pragma unroll
    for (int i = 0; i < 3; ++i) {
        int s  = t + 256 * i;               // 0..767
        int c  = s >> 3;
        int kc = (s & 7) ^ (c & 7);
        b_base[i] = wbT + (size_t)(col0 + c) * IN_DIM + kc * 8;
    }

    f32x4 acc[2][3] = {};

    for (int step = 0; step < KSTEPS; ++step) {
        int k0 = step * BK;
        // A: reg-stage fp32 -> bf16 -> ds_write_b128 (identical LDS layout)
        #pragma unroll
        for (int i = 0; i < 2; ++i) {
            float4 fa = *(const float4*)(a_base[i] + k0);
            float4 fb = *(const float4*)(a_base[i] + k0 + 4);
            uint4 rr;
            rr.x = bfpack(fa.x, fa.y);
            rr.y = bfpack(fa.z, fa.w);
            rr.z = bfpack(fb.x, fb.y);
            rr.w = bfpack(fb.z, fb.w);
            *(uint4*)(&As[(t + 256 * i) * 8]) = rr;
        }
        // B: direct-to-LDS DMA
        #pragma unroll
        for (int i = 0; i < 3; ++i)
            gload_lds16(b_base[i] + k0, &Bs[(t + 256 * i) * 8]);
        __syncthreads();                    // drains vmcnt + lgkmcnt

        #pragma unroll
        for (int ks = 0; ks < 2; ++ks) {
            int kc  = ks * 4 + lg;
            int kca = kc ^ sw;              // swizzled chunk index
            bf16x8 af[2], bfr[3];
            #pragma unroll
            for (int mi = 0; mi < 2; ++mi)
                af[mi] = *(const bf16x8*)(&As[((wr + mi * 16 + lr) * 8 + kca) * 8]);
            #pragma unroll
            for (int ni = 0; ni < 3; ++ni)
                bfr[ni] = *(const bf16x8*)(&Bs[((wc + ni * 16 + lr) * 8 + kca) * 8]);
            __builtin_amdgcn_s_setprio(1);
            #pragma unroll
            for (int mi = 0; mi < 2; ++mi)
                #pragma unroll
                for (int ni = 0; ni < 3; ++ni)
                    acc[mi][ni] = __builtin_amdgcn_mfma_f32_16x16x32_bf16(
                        af[mi], bfr[ni], acc[mi][ni], 0, 0, 0);
            __builtin_amdgcn_s_setprio(0);
        }
        __syncthreads();                    // reads done before next overwrite
    }

    // epilogue: C/D layout col=lane&15, row=(lane>>4)*4+reg
    #pragma unroll
    for (int mi = 0; mi < 2; ++mi) {
        #pragma unroll
        for (int rr = 0; rr < 4; ++rr) {
            int row = row0 + wr + mi * 16 + lg * 4 + rr;
            if (row >= N_NODES) continue;
            #pragma unroll
            for (int ni = 0; ni < 3; ++ni) {
                int col = col0 + wc + ni * 16 + lr;
                float v = acc[mi][ni][rr];
                if (col < 512)      xsb[(size_t)row * HC + col] = (short)f2bf(v);
                else if (col < 520) a_srcv[(size_t)row * 8 + (col - 512)] = v;
                else if (col < 528) a_dstv[(size_t)row * 8 + (col - 520)] = v;
            }
        }
    }
}

// ---------------------------------------------------------------------------
// ONE WAVE per destination node (4 independent waves/block, no barriers).
// Lane owns 8 channels of one head: per edge, one dwordx4 gather per lane,
// one weight compute, 8 FMAs.  LN via 6-step shfl_xor across the wave.
__global__ __launch_bounds__(256) void aggregate_ln(
        const int* __restrict__ off,
        const int* __restrict__ csr_src,
        const float* __restrict__ a_srcv,
        const float* __restrict__ a_dstv,
        const short* __restrict__ xsb,
        const float* __restrict__ bias,
        const float* __restrict__ gamma,
        const float* __restrict__ beta,
        const float* __restrict__ prelu_a,
        float* __restrict__ out) {
    int lane = threadIdx.x & 63;
    int n    = blockIdx.x * 4 + (threadIdx.x >> 6);   // grid 5000 x 4 waves = 20000
    int ch0  = lane * 8;
    int h    = lane >> 3;

    int start = off[n], end = off[n + 1];
    float ad  = a_dstv[(size_t)n * 8 + h];

    float acc[8] = {};
    float wsum = 0.f;

    int i = start;
    for (; i + 1 < end; i += 2) {
        int s0 = __builtin_amdgcn_readfirstlane(csr_src[i]);
        int s1 = __builtin_amdgcn_readfirstlane(csr_src[i + 1]);
        float sc0 = a_srcv[(size_t)s0 * 8 + h] + ad;
        float sc1 = a_srcv[(size_t)s1 * 8 + h] + ad;
        uint4 u0 = *(const uint4*)(xsb + (size_t)s0 * HC + ch0);
        uint4 u1 = *(const uint4*)(xsb + (size_t)s1 * HC + ch0);
        sc0 = (sc0 >= 0.f) ? sc0 : LEAKY * sc0;
        sc1 = (sc1 >= 0.f) ? sc1 : LEAKY * sc1;
        float w0 = __expf(sc0);
        float w1 = __expf(sc1);
        acc[0] = fmaf(w0, bf2f(u0.x & 0xffffu), acc[0]);
        acc[1] = fmaf(w0, bf2f(u0.x >> 16),     acc[1]);
        acc[2] = fmaf(w0, bf2f(u0.y & 0xffffu), acc[2]);
        acc[3] = fmaf(w0, bf2f(u0.y >> 16),     acc[3]);
        acc[4] = fmaf(w0, bf2f(u0.z & 0xffffu), acc[4]);
        acc[5] = fmaf(w0, bf2f(u0.z >> 16),     acc[5]);
        acc[6] = fmaf(w0, bf2f(u0.w & 0xffffu), acc[6]);
        acc[7] = fmaf(w0, bf2f(u0.w >> 16),     acc[7]);
        acc[0] = fmaf(w1, bf2f(u1.x & 0xffffu), acc[0]);
        acc[1] = fmaf(w1, bf2f(u1.x >> 16),     acc[1]);
        acc[2] = fmaf(w1, bf2f(u1.y & 0xffffu), acc[2]);
        acc[3] = fmaf(w1, bf2f(u1.y >> 16),     acc[3]);
        acc[4] = fmaf(w1, bf2f(u1.z & 0xffffu), acc[4]);
        acc[5] = fmaf(w1, bf2f(u1.z >> 16),     acc[5]);
        acc[6] = fmaf(w1, bf2f(u1.w & 0xffffu), acc[6]);
        acc[7] = fmaf(w1, bf2f(u1.w >> 16),     acc[7]);
        wsum += w0 + w1;
    }
    if (i < end) {
        int s0 = __builtin_amdgcn_readfirstlane(csr_src[i]);
        float sc0 = a_srcv[(size_t)s0 * 8 + h] + ad;
        uint4 u0 = *(const uint4*)(xsb + (size_t)s0 * HC + ch0);
        sc0 = (sc0 >= 0.f) ? sc0 : LEAKY * sc0;
        float w0 = __expf(sc0);
        acc[0] = fmaf(w0, bf2f(u0.x & 0xffffu), acc[0]);
        acc[1] = fmaf(w0, bf2f(u0.x >> 16),     acc[1]);
        acc[2] = fmaf(w0, bf2f(u0.y & 0xffffu), acc[2]);
        acc[3] = fmaf(w0, bf2f(u0.y >> 16),     acc[3]);
        acc[4] = fmaf(w0, bf2f(u0.z & 0xffffu), acc[4]);
        acc[5] = fmaf(w0, bf2f(u0.z >> 16),     acc[5]);
        acc[6] = fmaf(w0, bf2f(u0.w & 0xffffu), acc[6]);
        acc[7] = fmaf(w0, bf2f(u0.w >> 16),     acc[7]);
        wsum += w0;
    }

    float inv = 1.f / (wsum + 1e-16f);
    float4 b0 = *(const float4*)(bias + ch0);
    float4 b1 = *(const float4*)(bias + ch0 + 4);
    float v8[8];
    float psum = 0.f, psq = 0.f;
    const float bb[8] = {b0.x, b0.y, b0.z, b0.w, b1.x, b1.y, b1.z, b1.w};
    #pragma unroll
    for (int j = 0; j < 8; ++j) {
        v8[j] = acc[j] * inv + bb[j];
        psum += v8[j];
        psq  += v8[j] * v8[j];
    }
    #pragma unroll
    for (int o = 32; o > 0; o >>= 1) {
        psum += __shfl_xor(psum, o);
        psq  += __shfl_xor(psq, o);
    }
    float mu   = psum * (1.f / (float)HC);
    float var  = psq * (1.f / (float)HC) - mu * mu;
    float rstd = rsqrtf(var + LN_EPS);

    float4 g0 = *(const float4*)(gamma + ch0);
    float4 g1 = *(const float4*)(gamma + ch0 + 4);
    float4 e0 = *(const float4*)(beta + ch0);
    float4 e1 = *(const float4*)(beta + ch0 + 4);
    float4 p0 = *(const float4*)(prelu_a + ch0);
    float4 p1 = *(const float4*)(prelu_a + ch0 + 4);
    const float gg[8] = {g0.x, g0.y, g0.z, g0.w, g1.x, g1.y, g1.z, g1.w};
    const float ee[8] = {e0.x, e0.y, e0.z, e0.w, e1.x, e1.y, e1.z, e1.w};
    const float pp[8] = {p0.x, p0.y, p0.z, p0.w, p1.x, p1.y, p1.z, p1.w};
    float y[8];
    #pragma unroll
    for (int j = 0; j < 8; ++j) {
        float v = (v8[j] - mu) * rstd * gg[j] + ee[j];
        y[j] = (v >= 0.f) ? v : pp[j] * v;
    }
    float4* o4 = (float4*)(out + (size_t)n * HC + ch0);
    o4[0] = make_float4(y[0], y[1], y[2], y[3]);
    o4[1] = make_float4(y[4], y[5], y[6], y[7]);
}

// ---------------------------------------------------------------------------
extern "C" void kernel_launch(void* const* d_in, const int* in_sizes, int n_in,
                              void* d_out, int out_size, void* d_ws, size_t ws_size,
                              hipStream_t stream) {
    const float* x        = (const float*)d_in[0];
    const int*   ei       = (const int*)d_in[2];
    const float* Wsrc     = (const float*)d_in[4];
    const float* Wdst     = (const float*)d_in[5];
    const float* att_src  = (const float*)d_in[6];
    const float* att_dst  = (const float*)d_in[7];
    const float* bias     = (const float*)d_in[8];
    const float* gamma    = (const float*)d_in[9];
    const float* beta     = (const float*)d_in[10];
    const float* prelu_a  = (const float*)d_in[11];
    float* out            = (float*)d_out;

    char*  ws = (char*)d_ws;
    size_t o  = 0;
    auto alloc = [&](size_t bytes) -> void* {
        void* p = ws + o;
        o += (bytes + 255) & ~(size_t)255;
        return p;
    };
    short* wbT     = (short*)alloc(sizeof(short) * BCOLS * IN_DIM);        // 1.18 MB
    short* xsb     = (short*)alloc(sizeof(short) * (size_t)N_NODES * HC);  // 20.5 MB
    float* a_srcv  = (float*)alloc(sizeof(float) * N_NODES * 8);
    float* a_dstv  = (float*)alloc(sizeof(float) * N_NODES * 8);
    int*   deg     = (int*)alloc(sizeof(int) * N_NODES);
    int*   off     = (int*)alloc(sizeof(int) * (N_NODES + 1));
    int*   cursor  = (int*)alloc(sizeof(int) * N_NODES);
    int*   csr_src = (int*)alloc(sizeof(int) * N_EDGES);                   // 1.28 MB

    hipMemsetAsync(deg, 0, sizeof(int) * N_NODES, stream);

    deg_hist<<<DEG_BLOCKS, 256, 0, stream>>>(ei, deg);

    // 1024 prep blocks + 1 scan tail block (scan needs deg from deg_hist)
    prep_w_scan<<<IN_DIM + 1, 128, 0, stream>>>(Wsrc, Wdst, att_src, att_dst,
                                                wbT, deg, off, cursor);

    // GEMM blocks (reading fp32 x directly) + fused edge_scatter blocks
    gemm_scatter<<<NWG + DEG_BLOCKS, 256, 0, stream>>>(
        x, wbT, xsb, a_srcv, a_dstv, ei, cursor, csr_src);

    aggregate_ln<<<N_NODES / 4, 256, 0, stream>>>(
        off, csr_src, a_srcv, a_dstv, xsb, bias, gamma, beta, prelu_a, out);
}

// Round 14
// 147.628 us; speedup vs baseline: 1.3100x; 1.0023x over previous
//
#include <hip/hip_runtime.h>
#include <hip/hip_bf16.h>

#define N_NODES 20000
#define N_EDGES 320000
#define IN_DIM  1024
#define H_HEADS 8
#define C_CH    64
#define HC      512
#define LEAKY   0.2f
#define LN_EPS  1e-5f

// Extended (transposed) weight: rows 0..511 = W_src cols, 512..519 = att_src fold,
// 520..527 = att_dst fold, 528..575 zero pad.  wbT[col][k], bf16.
#define BCOLS 576

typedef short bf16x8 __attribute__((ext_vector_type(8)));
typedef float f32x4  __attribute__((ext_vector_type(4)));

__device__ __forceinline__ unsigned short f2bf(float f) {
    union { float f; unsigned int u; } c; c.f = f;
    unsigned int u = c.u;
    unsigned int r = (u + 0x7fffu + ((u >> 16) & 1u)) >> 16;   // RNE
    return (unsigned short)r;
}
__device__ __forceinline__ float bf2f(unsigned int h) {
    union { unsigned int u; float f; } c; c.u = h << 16; return c.f;
}
// HW packed f32->bf16 (RNE), 1 instr per 2 elements (gfx950; m214v22)
__device__ __forceinline__ unsigned int cvtpk(float lo, float hi) {
    unsigned int r;
    asm("v_cvt_pk_bf16_f32 %0, %1, %2" : "=v"(r) : "v"(lo), "v"(hi));
    return r;
}
__device__ __forceinline__ void gload_lds16(const void* g, void* l) {
    __builtin_amdgcn_global_load_lds(
        (const __attribute__((address_space(1))) unsigned int*)g,
        (__attribute__((address_space(3))) unsigned int*)l, 16, 0, 0);
}

// ---------------------------------------------------------------------------
#define DEG_BLOCKS 1250

__global__ __launch_bounds__(256) void deg_hist(
        const int* __restrict__ ei, int* __restrict__ deg) {
    int e = blockIdx.x * 256 + threadIdx.x;           // 1250*256 == N_EDGES
    atomicAdd(&deg[ei[N_EDGES + e]], 1);
}

// ---------------------------------------------------------------------------
// Build wbT (bf16, [BCOLS][IN_DIM]).  grid = 1024 prep blocks + 1 scan tail
// block.  Scan is vectorized: 125 threads x 160 elements (40 x int4).
__global__ void prep_w_scan(const float* __restrict__ Wsrc,
                            const float* __restrict__ Wdst,
                            const float* __restrict__ att_src,
                            const float* __restrict__ att_dst,
                            short* __restrict__ wbT,
                            const int* __restrict__ deg,
                            int* __restrict__ off,
                            int* __restrict__ cursor) {
    int t = threadIdx.x;                  // block = 128 threads

    if (blockIdx.x == IN_DIM) {           // ---- scan tail block
        __shared__ int wtot[2];
        int lane = t & 63, w = t >> 6;
        const int4* deg4 = (const int4*)deg;
        int s = 0;
        if (t < 125) {                    // 125*160 == N_NODES exactly
            #pragma unroll
            for (int j = 0; j < 40; ++j) {
                int4 u = deg4[t * 40 + j];
                s += u.x + u.y + u.z + u.w;
            }
        }
        int v = s;
        #pragma unroll
        for (int o = 1; o < 64; o <<= 1) {
            int u = __shfl_up(v, o);
            if (lane >= o) v += u;
        }
        if (lane == 63) wtot[w] = v;
        __syncthreads();
        int add = (w == 1) ? wtot[0] : 0;
        int run = add + v - s;            // exclusive prefix of this segment
        if (t < 125) {
            int4* off4 = (int4*)off;
            int4* cur4 = (int4*)cursor;
            #pragma unroll
            for (int j = 0; j < 40; ++j) {
                int4 u = deg4[t * 40 + j];
                int4 o_;
                o_.x = run;
                o_.y = o_.x + u.x;
                o_.z = o_.y + u.y;
                o_.w = o_.z + u.z;
                off4[t * 40 + j] = o_;
                cur4[t * 40 + j] = o_;
                run = o_.w + u.w;
            }
            if (t == 124) off[N_NODES] = run;
        }
        return;
    }

    int k = blockIdx.x;
    float4 v = *(const float4*)(Wsrc + (size_t)k * HC + t * 4);
    wbT[(size_t)(t * 4 + 0) * IN_DIM + k] = (short)f2bf(v.x);
    wbT[(size_t)(t * 4 + 1) * IN_DIM + k] = (short)f2bf(v.y);
    wbT[(size_t)(t * 4 + 2) * IN_DIM + k] = (short)f2bf(v.z);
    wbT[(size_t)(t * 4 + 3) * IN_DIM + k] = (short)f2bf(v.w);
    if (t < 16) {
        int h = t & 7;
        const float* W   = (t < 8) ? Wsrc : Wdst;
        const float* att = (t < 8) ? att_src : att_dst;
        float s = 0.f;
        #pragma unroll
        for (int c = 0; c < C_CH; ++c)
            s += W[(size_t)k * HC + h * C_CH + c] * att[h * C_CH + c];
        wbT[(size_t)(512 + t) * IN_DIM + k] = (short)f2bf(s);
    } else if (t < 64) {
        wbT[(size_t)(512 + t) * IN_DIM + k] = 0;   // pad cols 528..575
    }
}

// ---------------------------------------------------------------------------
// MFMA GEMM (R13 geometry: BM=64 x BN=96 x BK=64, 4 waves 2x2, 1878 blocks)
// now with a REAL 2-phase pipeline (T3 minimum recipe) + HW cvt_pk:
//   per step: issue A(next) reg-loads + B(next) global_load_lds  ->
//             compute(cur) [MFMA = latency cover]                ->
//             cvt_pk + ds_write A(next)  -> vmcnt(0)/lgkmcnt(0) barrier.
// LDS: A 2x8 KB + B 2x12 KB = 40 KB -> 4 blocks/CU.  Layout unchanged:
//   slot s = m*8 + kcp holds chunk kc = kcp ^ (m&7) of row m; fragment
//   ds_read_b128 uses kca = kc ^ (lr&7) -> 2-way = free.
// Blocks [0,NWG): GEMM.  Blocks [NWG,NWG+DEG_BLOCKS): CSR edge scatter.
#define BM 64
#define BN 96
#define BK 64
#define NCOLT (BCOLS / BN)                  // 6
#define NROWT ((N_NODES + BM - 1) / BM)     // 313
#define NWG (NCOLT * NROWT)                 // 1878
#define KSTEPS (IN_DIM / BK)                // 16
#define A_SLOTS (BM * BK / 8)               // 512 x 16B = 8 KB
#define B_SLOTS (BN * BK / 8)               // 768 x 16B = 12 KB

__global__ __launch_bounds__(256) void gemm_scatter(
        const float* __restrict__ x,
        const short* __restrict__ wbT,
        short* __restrict__ xsb,
        float* __restrict__ a_srcv,
        float* __restrict__ a_dstv,
        const int* __restrict__ ei,
        int* __restrict__ cursor,
        int* __restrict__ csr_src) {
    __shared__ short As[2][A_SLOTS * 8];    // 2 x 8 KB
    __shared__ short Bs[2][B_SLOTS * 8];    // 2 x 12 KB  (40 KB total)

    int t = threadIdx.x;

    // ---- scatter blocks: bare CSR scatter, sorted by dst
    if (blockIdx.x >= NWG) {
        int e = (blockIdx.x - NWG) * 256 + t;   // 1250*256 == N_EDGES exactly
        int d = ei[N_EDGES + e];
        int idx = atomicAdd(&cursor[d], 1);
        csr_src[idx] = ei[e];
        return;
    }

    // bijective XCD swizzle (m204): contiguous chunk of wgids per XCD
    int orig = blockIdx.x;
    const int q = NWG >> 3, r = NWG & 7;
    int xcd  = orig & 7;
    int wgid = (xcd < r ? xcd * (q + 1) : r * (q + 1) + (xcd - r) * q) + (orig >> 3);
    int col0 = (wgid % NCOLT) * BN;         // col tiles fastest -> A rows L2-local
    int row0 = (wgid / NCOLT) * BM;

    int lane = t & 63;
    int w    = t >> 6;
    int lr   = lane & 15;
    int lg   = lane >> 4;                   // k-group 0..3
    int sw   = lr & 7;                      // fragment-read swizzle key
    int wr   = (w >> 1) * 32;               // wave row offset (2x2 waves)
    int wc   = (w & 1) * 48;                // wave col offset

    // A staging source (fp32): slot s: m = s>>3, kcp = s&7; chunk kc = kcp^(m&7)
    const float* a_base[2];
    #pragma unroll
    for (int i = 0; i < 2; ++i) {
        int s  = t + 256 * i;               // 0..511
        int m  = s >> 3;
        int kc = (s & 7) ^ (m & 7);
        int gm = row0 + m;
        if (gm >= N_NODES) gm = N_NODES - 1;   // clamp (dead rows, in-bounds)
        a_base[i] = x + (size_t)gm * IN_DIM + kc * 8;
    }
    const short* b_base[3];
    #pragma unroll
    for (int i = 0; i < 3; ++i) {
        int s  = t + 256 * i;               // 0..767
        int c  = s >> 3;
        int kc = (s & 7) ^ (c & 7);
        b_base[i] = wbT + (size_t)(col0 + c) * IN_DIM + kc * 8;
    }

    f32x4 acc[2][3] = {};

#define A_WRITE(buf, fa0, fb0, fa1, fb1)                                      \
    do {                                                                      \
        uint4 r0, r1;                                                         \
        r0.x = cvtpk(fa0.x, fa0.y);  r0.y = cvtpk(fa0.z, fa0.w);              \
        r0.z = cvtpk(fb0.x, fb0.y);  r0.w = cvtpk(fb0.z, fb0.w);              \
        r1.x = cvtpk(fa1.x, fa1.y);  r1.y = cvtpk(fa1.z, fa1.w);              \
        r1.z = cvtpk(fb1.x, fb1.y);  r1.w = cvtpk(fb1.z, fb1.w);              \
        *(uint4*)(&As[buf][(t      ) * 8]) = r0;                              \
        *(uint4*)(&As[buf][(t + 256) * 8]) = r1;                              \
    } while (0)

#define COMPUTE(buf)                                                          \
    do {                                                                      \
        _Pragma("unroll")                                                     \
        for (int ks = 0; ks < 2; ++ks) {                                      \
            int kc  = ks * 4 + lg;                                            \
            int kca = kc ^ sw;                                                \
            bf16x8 af[2], bfr[3];                                             \
            _Pragma("unroll")                                                 \
            for (int mi = 0; mi < 2; ++mi)                                    \
                af[mi] = *(const bf16x8*)(&As[buf][((wr + mi * 16 + lr) * 8 + kca) * 8]); \
            _Pragma("unroll")                                                 \
            for (int ni = 0; ni < 3; ++ni)                                    \
                bfr[ni] = *(const bf16x8*)(&Bs[buf][((wc + ni * 16 + lr) * 8 + kca) * 8]); \
            __builtin_amdgcn_s_setprio(1);                                    \
            _Pragma("unroll")                                                 \
            for (int mi = 0; mi < 2; ++mi)                                    \
                _Pragma("unroll")                                             \
                for (int ni = 0; ni < 3; ++ni)                                \
                    acc[mi][ni] = __builtin_amdgcn_mfma_f32_16x16x32_bf16(    \
                        af[mi], bfr[ni], acc[mi][ni], 0, 0, 0);               \
            __builtin_amdgcn_s_setprio(0);                                    \
        }                                                                     \
    } while (0)

    // ---- prologue: stage tile 0 into buffer 0
    {
        float4 fa0 = *(const float4*)(a_base[0]);
        float4 fb0 = *(const float4*)(a_base[0] + 4);
        float4 fa1 = *(const float4*)(a_base[1]);
        float4 fb1 = *(const float4*)(a_base[1] + 4);
        #pragma unroll
        for (int i = 0; i < 3; ++i)
            gload_lds16(b_base[i], &Bs[0][(t + 256 * i) * 8]);
        A_WRITE(0, fa0, fb0, fa1, fb1);
        asm volatile("s_waitcnt vmcnt(0) lgkmcnt(0)" ::: "memory");
        __builtin_amdgcn_s_barrier();
    }

    int cur = 0;
    for (int step = 0; step < KSTEPS; ++step) {
        float4 fa0, fb0, fa1, fb1;
        if (step + 1 < KSTEPS) {
            int k1 = (step + 1) * BK;
            // issue next A reg-loads + next B DMA — covered by compute(cur)
            fa0 = *(const float4*)(a_base[0] + k1);
            fb0 = *(const float4*)(a_base[0] + k1 + 4);
            fa1 = *(const float4*)(a_base[1] + k1);
            fb1 = *(const float4*)(a_base[1] + k1 + 4);
            #pragma unroll
            for (int i = 0; i < 3; ++i)
                gload_lds16(b_base[i] + k1, &Bs[cur ^ 1][(t + 256 * i) * 8]);
        }

        COMPUTE(cur);                       // MFMA cluster = latency cover

        if (step + 1 < KSTEPS)
            A_WRITE(cur ^ 1, fa0, fb0, fa1, fb1);   // auto-waits A loads

        asm volatile("s_waitcnt vmcnt(0) lgkmcnt(0)" ::: "memory");
        __builtin_amdgcn_s_barrier();
        cur ^= 1;
    }
#undef A_WRITE
#undef COMPUTE

    // epilogue: C/D layout col=lane&15, row=(lane>>4)*4+reg
    #pragma unroll
    for (int mi = 0; mi < 2; ++mi) {
        #pragma unroll
        for (int rr = 0; rr < 4; ++rr) {
            int row = row0 + wr + mi * 16 + lg * 4 + rr;
            if (row >= N_NODES) continue;
            #pragma unroll
            for (int ni = 0; ni < 3; ++ni) {
                int col = col0 + wc + ni * 16 + lr;
                float v = acc[mi][ni][rr];
                if (col < 512)      xsb[(size_t)row * HC + col] = (short)f2bf(v);
                else if (col < 520) a_srcv[(size_t)row * 8 + (col - 512)] = v;
                else if (col < 528) a_dstv[(size_t)row * 8 + (col - 520)] = v;
            }
        }
    }
}

// ---------------------------------------------------------------------------
// ONE WAVE per destination node (4 independent waves/block, no barriers).
// Lane owns 8 channels of one head: per edge, one dwordx4 gather per lane,
// one weight compute, 8 FMAs.  LN via 6-step shfl_xor across the wave.
__global__ __launch_bounds__(256) void aggregate_ln(
        const int* __restrict__ off,
        const int* __restrict__ csr_src,
        const float* __restrict__ a_srcv,
        const float* __restrict__ a_dstv,
        const short* __restrict__ xsb,
        const float* __restrict__ bias,
        const float* __restrict__ gamma,
        const float* __restrict__ beta,
        const float* __restrict__ prelu_a,
        float* __restrict__ out) {
    int lane = threadIdx.x & 63;
    int n    = blockIdx.x * 4 + (threadIdx.x >> 6);   // grid 5000 x 4 waves = 20000
    int ch0  = lane * 8;
    int h    = lane >> 3;

    int start = off[n], end = off[n + 1];
    float ad  = a_dstv[(size_t)n * 8 + h];

    float acc[8] = {};
    float wsum = 0.f;

    int i = start;
    for (; i + 1 < end; i += 2) {
        int s0 = __builtin_amdgcn_readfirstlane(csr_src[i]);
        int s1 = __builtin_amdgcn_readfirstlane(csr_src[i + 1]);
        float sc0 = a_srcv[(size_t)s0 * 8 + h] + ad;
        float sc1 = a_srcv[(size_t)s1 * 8 + h] + ad;
        uint4 u0 = *(const uint4*)(xsb + (size_t)s0 * HC + ch0);
        uint4 u1 = *(const uint4*)(xsb + (size_t)s1 * HC + ch0);
        sc0 = (sc0 >= 0.f) ? sc0 : LEAKY * sc0;
        sc1 = (sc1 >= 0.f) ? sc1 : LEAKY * sc1;
        float w0 = __expf(sc0);
        float w1 = __expf(sc1);
        acc[0] = fmaf(w0, bf2f(u0.x & 0xffffu), acc[0]);
        acc[1] = fmaf(w0, bf2f(u0.x >> 16),     acc[1]);
        acc[2] = fmaf(w0, bf2f(u0.y & 0xffffu), acc[2]);
        acc[3] = fmaf(w0, bf2f(u0.y >> 16),     acc[3]);
        acc[4] = fmaf(w0, bf2f(u0.z & 0xffffu), acc[4]);
        acc[5] = fmaf(w0, bf2f(u0.z >> 16),     acc[5]);
        acc[6] = fmaf(w0, bf2f(u0.w & 0xffffu), acc[6]);
        acc[7] = fmaf(w0, bf2f(u0.w >> 16),     acc[7]);
        acc[0] = fmaf(w1, bf2f(u1.x & 0xffffu), acc[0]);
        acc[1] = fmaf(w1, bf2f(u1.x >> 16),     acc[1]);
        acc[2] = fmaf(w1, bf2f(u1.y & 0xffffu), acc[2]);
        acc[3] = fmaf(w1, bf2f(u1.y >> 16),     acc[3]);
        acc[4] = fmaf(w1, bf2f(u1.z & 0xffffu), acc[4]);
        acc[5] = fmaf(w1, bf2f(u1.z >> 16),     acc[5]);
        acc[6] = fmaf(w1, bf2f(u1.w & 0xffffu), acc[6]);
        acc[7] = fmaf(w1, bf2f(u1.w >> 16),     acc[7]);
        wsum += w0 + w1;
    }
    if (i < end) {
        int s0 = __builtin_amdgcn_readfirstlane(csr_src[i]);
        float sc0 = a_srcv[(size_t)s0 * 8 + h] + ad;
        uint4 u0 = *(const uint4*)(xsb + (size_t)s0 * HC + ch0);
        sc0 = (sc0 >= 0.f) ? sc0 : LEAKY * sc0;
        float w0 = __expf(sc0);
        acc[0] = fmaf(w0, bf2f(u0.x & 0xffffu), acc[0]);
        acc[1] = fmaf(w0, bf2f(u0.x >> 16),     acc[1]);
        acc[2] = fmaf(w0, bf2f(u0.y & 0xffffu), acc[2]);
        acc[3] = fmaf(w0, bf2f(u0.y >> 16),     acc[3]);
        acc[4] = fmaf(w0, bf2f(u0.z & 0xffffu), acc[4]);
        acc[5] = fmaf(w0, bf2f(u0.z >> 16),     acc[5]);
        acc[6] = fmaf(w0, bf2f(u0.w & 0xffffu), acc[6]);
        acc[7] = fmaf(w0, bf2f(u0.w >> 16),     acc[7]);
        wsum += w0;
    }

    float inv = 1.f / (wsum + 1e-16f);
    float4 b0 = *(const float4*)(bias + ch0);
    float4 b1 = *(const float4*)(bias + ch0 + 4);
    float v8[8];
    float psum = 0.f, psq = 0.f;
    const float bb[8] = {b0.x, b0.y, b0.z, b0.w, b1.x, b1.y, b1.z, b1.w};
    #pragma unroll
    for (int j = 0; j < 8; ++j) {
        v8[j] = acc[j] * inv + bb[j];
        psum += v8[j];
        psq  += v8[j] * v8[j];
    }
    #pragma unroll
    for (int o = 32; o > 0; o >>= 1) {
        psum += __shfl_xor(psum, o);
        psq  += __shfl_xor(psq, o);
    }
    float mu   = psum * (1.f / (float)HC);
    float var  = psq * (1.f / (float)HC) - mu * mu;
    float rstd = rsqrtf(var + LN_EPS);

    float4 g0 = *(const float4*)(gamma + ch0);
    float4 g1 = *(const float4*)(gamma + ch0 + 4);
    float4 e0 = *(const float4*)(beta + ch0);
    float4 e1 = *(const float4*)(beta + ch0 + 4);
    float4 p0 = *(const float4*)(prelu_a + ch0);
    float4 p1 = *(const float4*)(prelu_a + ch0 + 4);
    const float gg[8] = {g0.x, g0.y, g0.z, g0.w, g1.x, g1.y, g1.z, g1.w};
    const float ee[8] = {e0.x, e0.y, e0.z, e0.w, e1.x, e1.y, e1.z, e1.w};
    const float pp[8] = {p0.x, p0.y, p0.z, p0.w, p1.x, p1.y, p1.z, p1.w};
    float y[8];
    #pragma unroll
    for (int j = 0; j < 8; ++j) {
        float v = (v8[j] - mu) * rstd * gg[j] + ee[j];
        y[j] = (v >= 0.f) ? v : pp[j] * v;
    }
    float4* o4 = (float4*)(out + (size_t)n * HC + ch0);
    o4[0] = make_float4(y[0], y[1], y[2], y[3]);
    o4[1] = make_float4(y[4], y[5], y[6], y[7]);
}

// ---------------------------------------------------------------------------
extern "C" void kernel_launch(void* const* d_in, const int* in_sizes, int n_in,
                              void* d_out, int out_size, void* d_ws, size_t ws_size,
                              hipStream_t stream) {
    const float* x        = (const float*)d_in[0];
    const int*   ei       = (const int*)d_in[2];
    const float* Wsrc     = (const float*)d_in[4];
    const float* Wdst     = (const float*)d_in[5];
    const float* att_src  = (const float*)d_in[6];
    const float* att_dst  = (const float*)d_in[7];
    const float* bias     = (const float*)d_in[8];
    const float* gamma    = (const float*)d_in[9];
    const float* beta     = (const float*)d_in[10];
    const float* prelu_a  = (const float*)d_in[11];
    float* out            = (float*)d_out;

    char*  ws = (char*)d_ws;
    size_t o  = 0;
    auto alloc = [&](size_t bytes) -> void* {
        void* p = ws + o;
        o += (bytes + 255) & ~(size_t)255;
        return p;
    };
    short* wbT     = (short*)alloc(sizeof(short) * BCOLS * IN_DIM);        // 1.18 MB
    short* xsb     = (short*)alloc(sizeof(short) * (size_t)N_NODES * HC);  // 20.5 MB
    float* a_srcv  = (float*)alloc(sizeof(float) * N_NODES * 8);
    float* a_dstv  = (float*)alloc(sizeof(float) * N_NODES * 8);
    int*   deg     = (int*)alloc(sizeof(int) * N_NODES);
    int*   off     = (int*)alloc(sizeof(int) * (N_NODES + 1));
    int*   cursor  = (int*)alloc(sizeof(int) * N_NODES);
    int*   csr_src = (int*)alloc(sizeof(int) * N_EDGES);                   // 1.28 MB

    hipMemsetAsync(deg, 0, sizeof(int) * N_NODES, stream);

    deg_hist<<<DEG_BLOCKS, 256, 0, stream>>>(ei, deg);

    // 1024 prep blocks + 1 scan tail block (scan needs deg from deg_hist)
    prep_w_scan<<<IN_DIM + 1, 128, 0, stream>>>(Wsrc, Wdst, att_src, att_dst,
                                                wbT, deg, off, cursor);

    // GEMM blocks (reading fp32 x directly) + fused edge_scatter blocks
    gemm_scatter<<<NWG + DEG_BLOCKS, 256, 0, stream>>>(
        x, wbT, xsb, a_srcv, a_dstv, ei, cursor, csr_src);

    aggregate_ln<<<N_NODES / 4, 256, 0, stream>>>(
        off, csr_src, a_srcv, a_dstv, xsb, bias, gamma, beta, prelu_a, out);
}